// Round 13
// baseline (349.872 us; speedup 1.0000x reference)
//
#include <hip/hip_runtime.h>
#include <hip/hip_fp16.h>
#include <math.h>

// ---------------------------------------------------------------------------
// ADCGNN amazon: N=50000, E=1.6M, IN=128, H=64, C=2, K=3
//
// R14: src-index rotation: tail 89.5->84. [362]
// R15: grid-concat fusion. [344]
// R16: u1s fp8 rows (L2-resident table): tail 84.5->77.6. [329.7 best]
//      BUT fused3_k exposed: 85us @ occ 11%, VALU 7% (196 dense blocks,
//      fp32 weight streams, stride-36 LDS 8-way conflicts). Also latent bug:
//      dense2res read dinv before csr_build wrote it (passed only via
//      workspace persistence across warmup).
// R17 (this round): dense2res -> wave-per-node fp16 dot2 (tail's proven
//      structure; W2h/Wresh 8KB each, L1-resident; 12.5k blocks). dinv
//      ordering fixed: per-node degree via global atomics in fused1,
//      dinv computed in scan_dinv_k before fused3.
//
// Pipeline:
//   K1: bucket_count+degN || dense1 || pack_w (Wf1,W3,W2,Wres -> fp16)
//   K2: bucket_scan || dinv = rsqrt(degN)
//   K3: bucket_scatter || dense2res (wave/node dot2)
//   csr_build (rowPtr, srcSorted only)
//   spmm1 (rotated fp16 gather -> u fp32, u1s fp8, ta)
//   tail  (rotated fp8 gather + softmax + dot2 GEMVs)
// ---------------------------------------------------------------------------

#define BSHIFT 7
#define BNODES 128
#define BMAX   512
#define EPT    32
#define CHUNK  (256 * EPT)
#define CAP    8192
#define F8SCALE 8.0f
#define F8INV  0.125f

typedef _Float16 h2v __attribute__((ext_vector_type(2)));
typedef float f2v __attribute__((ext_vector_type(2)));

__device__ __forceinline__ h2v as_h2(unsigned int u) {
    union { unsigned int u; h2v h; } c; c.u = u; return c.h;
}

__device__ __forceinline__ void fma4(float4& acc, float s, const float4 w) {
    acc.x += s * w.x; acc.y += s * w.y; acc.z += s * w.z; acc.w += s * w.w;
}

__device__ __forceinline__ float2 pack_half4(float x, float y, float z, float w) {
    union { __half2 h[2]; float2 f; } u;
    u.h[0] = __floats2half2_rn(x, y);
    u.h[1] = __floats2half2_rn(z, w);
    return u.f;
}

__device__ __forceinline__ void acch4(float4& a, float2 p) {
    union { float2 f; __half2 h[2]; } u; u.f = p;
    float2 lo = __half22float2(u.h[0]);
    float2 hi = __half22float2(u.h[1]);
    a.x += lo.x; a.y += lo.y; a.z += hi.x; a.w += hi.y;
}

// depth-2 fp16 pairwise tree over 4 edges, then fp32 accumulate.
__device__ __forceinline__ void accq(float4& a, float2 pA, float2 pB,
                                     float2 pC, float2 pD) {
    union { float2 f; __half2 h[2]; } A, B, C, D;
    A.f = pA; B.f = pB; C.f = pC; D.f = pD;
    __half2 s0 = __hadd2(__hadd2(A.h[0], B.h[0]), __hadd2(C.h[0], D.h[0]));
    __half2 s1 = __hadd2(__hadd2(A.h[1], B.h[1]), __hadd2(C.h[1], D.h[1]));
    float2 lo = __half22float2(s0), hi = __half22float2(s1);
    a.x += lo.x; a.y += lo.y; a.z += hi.x; a.w += hi.y;
}

__device__ __forceinline__ void accd(float4& a, float2 pA, float2 pB) {
    union { float2 f; __half2 h[2]; } A, B;
    A.f = pA; B.f = pB;
    __half2 s0 = __hadd2(A.h[0], B.h[0]);
    __half2 s1 = __hadd2(A.h[1], B.h[1]);
    float2 lo = __half22float2(s0), hi = __half22float2(s1);
    a.x += lo.x; a.y += lo.y; a.z += hi.x; a.w += hi.y;
}

// fp8 (e4m3) unpack-accumulate: 4 fp8 in a uint -> fp32 accumulate.
__device__ __forceinline__ void accf8(float4& a, unsigned int v) {
    f2v lo = __builtin_amdgcn_cvt_pk_f32_fp8(v, false);
    f2v hi = __builtin_amdgcn_cvt_pk_f32_fp8(v, true);
    a.x += lo[0]; a.y += lo[1]; a.z += hi[0]; a.w += hi[1];
}

// pack one 64-col fp16 pair-matrix entry: Wh[kk*64+j]=half2(W[2kk][j],W[2kk+1][j])
__device__ __forceinline__ void pack_pair(const float* __restrict__ W,
                                          unsigned int* __restrict__ Wh, int r) {
    int kk = r >> 6, j = r & 63;
    union { __half2 h; unsigned int u; } c;
    c.h = __floats2half2_rn(W[(2 * kk) * 64 + j], W[(2 * kk + 1) * 64 + j]);
    Wh[r] = c.u;
}

// ----------------------------- K1: count/deg || dense1 || pack_w -----------

__global__ __launch_bounds__(256) void fused1_k(const int* __restrict__ dst,
                                                int* __restrict__ bucketCount,
                                                int* __restrict__ degN,
                                                int E, int B,
                                                const float* __restrict__ Xg,
                                                const float* __restrict__ W1,
                                                const float* __restrict__ b1,
                                                float* __restrict__ h1, int N,
                                                const float* __restrict__ Wf1,
                                                const float* __restrict__ W3,
                                                const float* __restrict__ W2,
                                                const float* __restrict__ Wres,
                                                unsigned int* __restrict__ Wf1h,
                                                unsigned int* __restrict__ W3h,
                                                unsigned int* __restrict__ W2h,
                                                unsigned int* __restrict__ Wresh,
                                                int eb, int d1b) {
    __shared__ float smem[256 * 36];
    int bid = blockIdx.x;
    if (bid < eb) {
        // ---- bucket_count + per-node degree ----
        int* cnt = (int*)smem;
        for (int i = threadIdx.x; i < B; i += 256) cnt[i] = 0;
        __syncthreads();
        int base = bid * CHUNK;
        #pragma unroll
        for (int t = 0; t < EPT; t++) {
            int e = base + t * 256 + threadIdx.x;
            if (e < E) {
                int d = dst[e];
                atomicAdd(&cnt[d >> BSHIFT], 1);
                atomicAdd(&degN[d], 1);
            }
        }
        __syncthreads();
        for (int i = threadIdx.x; i < B; i += 256)
            if (cnt[i] > 0) atomicAdd(&bucketCount[i], cnt[i]);
        return;
    }
    bid -= eb;
    if (bid < d1b) {
        // ---- dense1: 256 nodes/block, two half-row LDS rounds ----
        int n0 = bid * 256;
        int n = n0 + threadIdx.x;
        bool act = (n < N);
        const float4* W = (const float4*)W1;
        const float4* Bb = (const float4*)b1;
        float4 acc[16];
        #pragma unroll
        for (int j = 0; j < 16; j++) acc[j] = Bb[j];
        if (act) {
            const float4* X = (const float4*)Xg + (size_t)n * 32;
            float4 a = X[0];
            #pragma unroll 1
            for (int kc = 0; kc < 32; kc++) {
                float4 an = a;
                if (kc + 1 < 32) an = X[kc + 1];
                const float4* wrow = W + kc * 64;
                #pragma unroll
                for (int j = 0; j < 16; j++) {
                    fma4(acc[j], a.x, wrow[j]);
                    fma4(acc[j], a.y, wrow[16 + j]);
                    fma4(acc[j], a.z, wrow[32 + j]);
                    fma4(acc[j], a.w, wrow[48 + j]);
                }
                a = an;
            }
        }
        #pragma unroll
        for (int j = 0; j < 16; j++) {
            float4 v = acc[j];
            acc[j] = make_float4(fmaxf(v.x, 0.f), fmaxf(v.y, 0.f),
                                 fmaxf(v.z, 0.f), fmaxf(v.w, 0.f));
        }
        float4* o4 = (float4*)h1;
        #pragma unroll
        for (int r2 = 0; r2 < 2; r2++) {
            __syncthreads();
            float* myrow = &smem[threadIdx.x * 36];
            #pragma unroll
            for (int j = 0; j < 8; j++) *(float4*)&myrow[4 * j] = acc[r2 * 8 + j];
            __syncthreads();
            #pragma unroll
            for (int r = 0; r < 8; r++) {
                int idx = r * 256 + threadIdx.x;
                int row = idx >> 3, col = idx & 7;
                int gn = n0 + row;
                if (gn < N)
                    o4[(size_t)gn * 16 + r2 * 8 + col] =
                        *(float4*)&smem[row * 36 + col * 4];
            }
        }
        return;
    }
    bid -= d1b;
    // ---- pack_w: Wf1h(4096) | W3h(2048) | W2h(2048) | Wresh(2048) ----
    int t = bid * 256 + threadIdx.x;
    if (t < 4096) pack_pair(Wf1, Wf1h, t);
    else if (t < 6144) pack_pair(W3, W3h, t - 4096);
    else if (t < 8192) pack_pair(W2, W2h, t - 6144);
    else if (t < 10240) pack_pair(Wres, Wresh, t - 8192);
}

// ----------------------------- K2: scan || dinv -----------------------------

__global__ __launch_bounds__(256) void scan_dinv_k(const int* __restrict__ bucketCount,
                                                   int* __restrict__ bucketPtr,
                                                   int* __restrict__ bucketCursor,
                                                   int* __restrict__ rowPtr,
                                                   const int* __restrict__ degN,
                                                   float* __restrict__ dinv,
                                                   int B, int N, int E) {
    if (blockIdx.x == 0) {
        if (threadIdx.x >= 64) return;
        int lane = threadIdx.x;
        const int PT = (BMAX + 63) / 64;
        int v[PT]; int s = 0;
        #pragma unroll
        for (int t = 0; t < PT; t++) {
            int i = lane * PT + t;
            v[t] = (i < B) ? bucketCount[i] : 0;
            s += v[t];
        }
        int x = s;
        #pragma unroll
        for (int off = 1; off < 64; off <<= 1) {
            int y = __shfl_up(x, off, 64);
            if (lane >= off) x += y;
        }
        int run = x - s;
        #pragma unroll
        for (int t = 0; t < PT; t++) {
            int i = lane * PT + t;
            if (i < B) { bucketPtr[i] = run; bucketCursor[i] = run; }
            run += v[t];
        }
        if (lane == 63) bucketPtr[B] = x;
        if (lane == 0) rowPtr[N] = E;
        return;
    }
    int n = (blockIdx.x - 1) * 256 + threadIdx.x;
    if (n < N) {
        int dg = degN[n];
        dinv[n] = rsqrtf((float)(dg > 1 ? dg : 1));
    }
}

// ----------------------------- K3: scatter || dense2res (wave/node) --------

#define D2_HPAD 72   // halves per wave slice (64 used; 16B-aligned)

__global__ __launch_bounds__(256) void fused3_k(const int* __restrict__ src,
                                                const int* __restrict__ dst,
                                                int* __restrict__ bucketCursor,
                                                int* __restrict__ ebuf,
                                                int E, int B,
                                                const float* __restrict__ h1,
                                                const unsigned int* __restrict__ W2h,
                                                const float* __restrict__ b2,
                                                const unsigned int* __restrict__ Wresh,
                                                const float* __restrict__ bres,
                                                const float* __restrict__ Wattn,
                                                const float* __restrict__ dinv,
                                                float* __restrict__ hg,
                                                __half* __restrict__ hsh,
                                                float* __restrict__ resg,
                                                float* __restrict__ thv, int N,
                                                int eb) {
    __shared__ int s_cnt[BMAX];
    __shared__ int s_base[BMAX];
    __shared__ int s_cur[BMAX];
    __shared__ _Float16 bsl[4 * D2_HPAD];
    int bid = blockIdx.x;
    if (bid < eb) {
        // ---- bucket_scatter ----
        for (int i = threadIdx.x; i < B; i += 256) { s_cnt[i] = 0; s_cur[i] = 0; }
        __syncthreads();
        int cbase = bid * CHUNK;
        int d[EPT];
        #pragma unroll
        for (int t = 0; t < EPT; t++) {
            int e = cbase + t * 256 + threadIdx.x;
            d[t] = (e < E) ? dst[e] : -1;
            if (d[t] >= 0) atomicAdd(&s_cnt[d[t] >> BSHIFT], 1);
        }
        __syncthreads();
        for (int i = threadIdx.x; i < B; i += 256)
            if (s_cnt[i] > 0) s_base[i] = atomicAdd(&bucketCursor[i], s_cnt[i]);
        __syncthreads();
        #pragma unroll
        for (int t = 0; t < EPT; t++) {
            int e = cbase + t * 256 + threadIdx.x;
            if (d[t] >= 0) {
                int b = d[t] >> BSHIFT;
                int c = atomicAdd(&s_cur[b], 1);
                int pack = (src[e] & 0xFFFF) | ((d[t] & (BNODES - 1)) << 16);
                ebuf[s_base[b] + c] = pack;
            }
        }
        return;
    }
    bid -= eb;
    // ---- dense2res: wave per node, fp16 dot2 GEMVs ----
    int w = threadIdx.x >> 6;
    int lane = threadIdx.x & 63;
    int node = bid * 4 + w;
    if (node >= N) return;
    float h1j = h1[(size_t)node * 64 + lane];
    float di = dinv[node];
    float waj = Wattn[lane];
    _Float16* bsh = &bsl[w * D2_HPAD];
    bsh[lane] = (_Float16)h1j;
    // h = relu(h1 @ W2 + b2): 32 packed pairs, 4 split chains
    float t0 = b2[lane], t1 = 0.f, t2 = 0.f, t3 = 0.f;
    #pragma unroll 1
    for (int kk = 0; kk < 32; kk += 4) {
        uint4 br = *(const uint4*)&bsh[2 * kk];
        unsigned int w0_ = W2h[(kk + 0) * 64 + lane];
        unsigned int w1_ = W2h[(kk + 1) * 64 + lane];
        unsigned int w2_ = W2h[(kk + 2) * 64 + lane];
        unsigned int w3_ = W2h[(kk + 3) * 64 + lane];
        t0 = __builtin_amdgcn_fdot2(as_h2(br.x), as_h2(w0_), t0, false);
        t1 = __builtin_amdgcn_fdot2(as_h2(br.y), as_h2(w1_), t1, false);
        t2 = __builtin_amdgcn_fdot2(as_h2(br.z), as_h2(w2_), t2, false);
        t3 = __builtin_amdgcn_fdot2(as_h2(br.w), as_h2(w3_), t3, false);
    }
    float hv = fmaxf((t0 + t1) + (t2 + t3), 0.f);
    // th = h . Wattn
    float th = hv * waj;
    #pragma unroll
    for (int m = 1; m < 64; m <<= 1) th += __shfl_xor(th, m, 64);
    if (lane == 0) thv[node] = th;
    // stores: h (f32), hs (f16 * dinv)
    hg[(size_t)node * 64 + lane] = hv;
    hsh[(size_t)node * 64 + lane] = (__half)(hv * di);
    // res = h @ Wres + bres  (stage h fp16; in-order DS per wave)
    bsh[lane] = (_Float16)hv;
    float g0 = bres[lane], g1 = 0.f, g2 = 0.f, g3 = 0.f;
    #pragma unroll 1
    for (int kk = 0; kk < 32; kk += 4) {
        uint4 br = *(const uint4*)&bsh[2 * kk];
        unsigned int w0_ = Wresh[(kk + 0) * 64 + lane];
        unsigned int w1_ = Wresh[(kk + 1) * 64 + lane];
        unsigned int w2_ = Wresh[(kk + 2) * 64 + lane];
        unsigned int w3_ = Wresh[(kk + 3) * 64 + lane];
        g0 = __builtin_amdgcn_fdot2(as_h2(br.x), as_h2(w0_), g0, false);
        g1 = __builtin_amdgcn_fdot2(as_h2(br.y), as_h2(w1_), g1, false);
        g2 = __builtin_amdgcn_fdot2(as_h2(br.z), as_h2(w2_), g2, false);
        g3 = __builtin_amdgcn_fdot2(as_h2(br.w), as_h2(w3_), g3, false);
    }
    resg[(size_t)node * 64 + lane] = (g0 + g1) + (g2 + g3);
}

// ----------------------------- csr_build ------------------------------------

__global__ __launch_bounds__(256) void csr_build_k(const int* __restrict__ ebuf,
                                                   const int* __restrict__ bucketPtr,
                                                   int* __restrict__ rowPtr,
                                                   int* __restrict__ srcSorted,
                                                   int N) {
    __shared__ int deg[BNODES];
    __shared__ int rp[BNODES + 1];
    __shared__ int cur[BNODES];
    __shared__ int stage[CAP];
    int b = blockIdx.x;
    int nodeBase = b << BSHIFT;
    int nNodes = min(BNODES, N - nodeBase);
    int eBase = bucketPtr[b];
    int eCnt = bucketPtr[b + 1] - eBase;
    for (int i = threadIdx.x; i < BNODES; i += 256) deg[i] = 0;
    __syncthreads();
    for (int i = threadIdx.x; i < eCnt; i += 256)
        atomicAdd(&deg[(ebuf[eBase + i] >> 16) & (BNODES - 1)], 1);
    __syncthreads();
    if (threadIdx.x < 64) {
        int lane = threadIdx.x;
        int d0 = deg[2 * lane], d1 = deg[2 * lane + 1];
        int s = d0 + d1;
        int x = s;
        #pragma unroll
        for (int off = 1; off < 64; off <<= 1) {
            int y = __shfl_up(x, off, 64);
            if (lane >= off) x += y;
        }
        int ex = x - s;
        rp[2 * lane] = ex;
        rp[2 * lane + 1] = ex + d0;
        cur[2 * lane] = ex;
        cur[2 * lane + 1] = ex + d0;
        if (lane == 63) rp[BNODES] = x;
    }
    __syncthreads();
    for (int j = threadIdx.x; j < nNodes; j += 256)
        rowPtr[nodeBase + j] = eBase + rp[j];
    if (eCnt <= CAP) {
        for (int i = threadIdx.x; i < eCnt; i += 256) {
            int p = ebuf[eBase + i];
            int ld = (p >> 16) & (BNODES - 1);
            int pos = atomicAdd(&cur[ld], 1);
            stage[pos] = p & 0xFFFF;
        }
        __syncthreads();
        for (int i = threadIdx.x; i < eCnt; i += 256)
            srcSorted[eBase + i] = stage[i];
    } else {
        for (int i = threadIdx.x; i < eCnt; i += 256) {
            int p = ebuf[eBase + i];
            int ld = (p >> 16) & (BNODES - 1);
            int pos = atomicAdd(&cur[ld], 1);
            srcSorted[eBase + pos] = p & 0xFFFF;
        }
    }
}

// ----------------------------- SPMM (spmm1) --------------------------------
// Wave per node (4/block). Rotated-index fp16 gather; writes u (fp32),
// u1s (fp8 e4m3, x8 scale), ta.

__global__ __launch_bounds__(256) void spmm_k(const float2* __restrict__ xs,
                                              const int* __restrict__ srcs,
                                              const int* __restrict__ rowPtr,
                                              const float* __restrict__ dinv,
                                              const float* __restrict__ Wattn,
                                              float4* __restrict__ u,
                                              unsigned int* __restrict__ us,
                                              float* __restrict__ tav, int N) {
    int node = (blockIdx.x * 256 + threadIdx.x) >> 6;
    if (node >= N) return;
    int lane = threadIdx.x & 63;
    int sub = lane >> 4;
    int q = lane & 15;
    int s0 = rowPtr[node], s1 = rowPtr[node + 1];
    float4 a0 = make_float4(0.f, 0.f, 0.f, 0.f);
    int i = s0 + sub;
    if (i + 12 < s1) {
        int cA = srcs[i], cB = srcs[i + 4], cC = srcs[i + 8], cD = srcs[i + 12];
        i += 16;
        for (; i + 12 < s1; i += 16) {
            int nA = srcs[i], nB = srcs[i + 4], nC = srcs[i + 8], nD = srcs[i + 12];
            float2 vA = xs[(size_t)cA * 16 + q];
            float2 vB = xs[(size_t)cB * 16 + q];
            float2 vC = xs[(size_t)cC * 16 + q];
            float2 vD = xs[(size_t)cD * 16 + q];
            accq(a0, vA, vB, vC, vD);
            cA = nA; cB = nB; cC = nC; cD = nD;
        }
        float2 vA = xs[(size_t)cA * 16 + q];
        float2 vB = xs[(size_t)cB * 16 + q];
        float2 vC = xs[(size_t)cC * 16 + q];
        float2 vD = xs[(size_t)cD * 16 + q];
        accq(a0, vA, vB, vC, vD);
    }
    for (; i + 4 < s1; i += 8) {
        int sA = srcs[i];
        int sB = srcs[i + 4];
        float2 vA = xs[(size_t)sA * 16 + q];
        float2 vB = xs[(size_t)sB * 16 + q];
        accd(a0, vA, vB);
    }
    if (i < s1) {
        float2 vA = xs[(size_t)srcs[i] * 16 + q];
        acch4(a0, vA);
    }
    #pragma unroll
    for (int m = 16; m < 64; m <<= 1) {
        a0.x += __shfl_xor(a0.x, m, 64);
        a0.y += __shfl_xor(a0.y, m, 64);
        a0.z += __shfl_xor(a0.z, m, 64);
        a0.w += __shfl_xor(a0.w, m, 64);
    }
    if (sub == 0) {
        float di = dinv[node];
        float4 r = make_float4(a0.x * di, a0.y * di, a0.z * di, a0.w * di);
        u[(size_t)node * 16 + q] = r;
        float sc = di * F8SCALE;
        unsigned int pk = 0;
        pk = __builtin_amdgcn_cvt_pk_fp8_f32(r.x * sc, r.y * sc, pk, false);
        pk = __builtin_amdgcn_cvt_pk_fp8_f32(r.z * sc, r.w * sc, pk, true);
        us[(size_t)node * 16 + q] = pk;
        float4 w = ((const float4*)Wattn)[q];
        float p = r.x * w.x + r.y * w.y + r.z * w.z + r.w * w.w;
        #pragma unroll
        for (int m = 1; m < 16; m <<= 1) p += __shfl_xor(p, m, 64);
        if (lane == 0) tav[node] = p;
    }
}

// ----------------------------- fused spmm2 + tail --------------------------

#define TL_PAD 68
#define BS_HPAD 136

__global__ __launch_bounds__(256) void tail_k(const unsigned int* __restrict__ u1s,
                                              const int* __restrict__ srcs,
                                              const int* __restrict__ rowPtr,
                                              const float* __restrict__ dinv,
                                              const float* __restrict__ hg,
                                              const float* __restrict__ u1g,
                                              const float* __restrict__ resg,
                                              const float* __restrict__ thv,
                                              const float* __restrict__ tav,
                                              const float* __restrict__ Wattn,
                                              const float* __restrict__ battn,
                                              const unsigned int* __restrict__ Wf1h,
                                              const float* __restrict__ bf1,
                                              const float* __restrict__ Wf2,
                                              const float* __restrict__ bf2,
                                              const unsigned int* __restrict__ W3h,
                                              const float* __restrict__ b3,
                                              const float* __restrict__ W4,
                                              const float* __restrict__ b4,
                                              float2* __restrict__ out, int N) {
    __shared__ float lds[4 * TL_PAD];
    __shared__ _Float16 bsl[4 * BS_HPAD];
    int w = threadIdx.x >> 6;
    int lane = threadIdx.x & 63;
    int node = blockIdx.x * 4 + w;
    if (node >= N) return;
    int sub = lane >> 4, q = lane & 15;
    float hj = hg[(size_t)node * 64 + lane];
    float u1j = u1g[(size_t)node * 64 + lane];
    float resj = resg[(size_t)node * 64 + lane];
    float th = thv[node], ta = tav[node], ba = battn[0];
    float waj = Wattn[lane];
    float dinv_n = dinv[node] * F8INV;
    {
        int s0 = rowPtr[node], s1 = rowPtr[node + 1];
        float4 a0 = make_float4(0.f, 0.f, 0.f, 0.f);
        float4 a1 = a0;
        int i = s0 + sub;
        if (i + 12 < s1) {
            int cA = srcs[i], cB = srcs[i + 4], cC = srcs[i + 8], cD = srcs[i + 12];
            i += 16;
            for (; i + 12 < s1; i += 16) {
                int nA = srcs[i], nB = srcs[i + 4], nC = srcs[i + 8], nD = srcs[i + 12];
                unsigned int vA = u1s[(size_t)cA * 16 + q];
                unsigned int vB = u1s[(size_t)cB * 16 + q];
                unsigned int vC = u1s[(size_t)cC * 16 + q];
                unsigned int vD = u1s[(size_t)cD * 16 + q];
                accf8(a0, vA); accf8(a1, vB); accf8(a0, vC); accf8(a1, vD);
                cA = nA; cB = nB; cC = nC; cD = nD;
            }
            unsigned int vA = u1s[(size_t)cA * 16 + q];
            unsigned int vB = u1s[(size_t)cB * 16 + q];
            unsigned int vC = u1s[(size_t)cC * 16 + q];
            unsigned int vD = u1s[(size_t)cD * 16 + q];
            accf8(a0, vA); accf8(a1, vB); accf8(a0, vC); accf8(a1, vD);
        }
        for (; i + 4 < s1; i += 8) {
            unsigned int vA = u1s[(size_t)srcs[i] * 16 + q];
            unsigned int vB = u1s[(size_t)srcs[i + 4] * 16 + q];
            accf8(a0, vA); accf8(a1, vB);
        }
        if (i < s1) {
            unsigned int vA = u1s[(size_t)srcs[i] * 16 + q];
            accf8(a0, vA);
        }
        a0.x += a1.x; a0.y += a1.y; a0.z += a1.z; a0.w += a1.w;
        #pragma unroll
        for (int m = 16; m < 64; m <<= 1) {
            a0.x += __shfl_xor(a0.x, m, 64);
            a0.y += __shfl_xor(a0.y, m, 64);
            a0.z += __shfl_xor(a0.z, m, 64);
            a0.w += __shfl_xor(a0.w, m, 64);
        }
        if (sub == 0) {
            *(float4*)&lds[w * TL_PAD + q * 4] =
                make_float4(a0.x * dinv_n, a0.y * dinv_n,
                            a0.z * dinv_n, a0.w * dinv_n);
        }
    }
    float u2j = lds[w * TL_PAD + lane];
    float tb = u2j * waj;
    #pragma unroll
    for (int m = 1; m < 64; m <<= 1) tb += __shfl_xor(tb, m, 64);
    float s0 = 0.75f * th + 1.5f * ta + 0.75f * tb + ba;
    float s1 = 1.5f * th - 1.5f * tb + ba;
    float s2 = 0.75f * th - 1.5f * ta + 0.75f * tb + ba;
    float mx = fmaxf(s0, fmaxf(s1, s2));
    float e0 = expf(s0 - mx), e1 = expf(s1 - mx), e2 = expf(s2 - mx);
    float inv = 1.f / (e0 + e1 + e2);
    float w0 = e0 * inv, w1 = e1 * inv, w2 = e2 * inv;
    float ca = 0.75f * w0 + 1.5f * w1 + 0.75f * w2;
    float cb = 1.5f * (w0 - w2);
    float cc = 0.75f * w0 - 1.5f * w1 + 0.75f * w2;
    float afj = ca * hj + cb * u1j + cc * u2j;
    _Float16* bsh = &bsl[w * BS_HPAD];
    bsh[lane] = (_Float16)afj;
    bsh[64 + lane] = (_Float16)hj;
    float t0 = bf1[lane], t1 = 0.f, t2 = 0.f, t3 = 0.f;
    #pragma unroll 1
    for (int kk = 0; kk < 64; kk += 4) {
        uint4 br = *(const uint4*)&bsh[2 * kk];
        unsigned int w0_ = Wf1h[(kk + 0) * 64 + lane];
        unsigned int w1_ = Wf1h[(kk + 1) * 64 + lane];
        unsigned int w2_ = Wf1h[(kk + 2) * 64 + lane];
        unsigned int w3_ = Wf1h[(kk + 3) * 64 + lane];
        t0 = __builtin_amdgcn_fdot2(as_h2(br.x), as_h2(w0_), t0, false);
        t1 = __builtin_amdgcn_fdot2(as_h2(br.y), as_h2(w1_), t1, false);
        t2 = __builtin_amdgcn_fdot2(as_h2(br.z), as_h2(w2_), t2, false);
        t3 = __builtin_amdgcn_fdot2(as_h2(br.w), as_h2(w3_), t3, false);
    }
    float t = fmaxf((t0 + t1) + (t2 + t3), 0.f);
    float fwacc = t * Wf2[lane];
    #pragma unroll
    for (int m = 1; m < 64; m <<= 1) fwacc += __shfl_xor(fwacc, m, 64);
    float fw = 1.f / (1.f + expf(-(fwacc + bf2[0])));
    float fj = 0.1f * fw * afj + (1.f - fw) * hj + 0.8f * resj;
    bsh[lane] = (_Float16)fj;
    float g0 = b3[lane], g1 = 0.f, g2 = 0.f, g3 = 0.f;
    #pragma unroll 1
    for (int kk = 0; kk < 32; kk += 4) {
        uint4 br = *(const uint4*)&bsh[2 * kk];
        unsigned int w0_ = W3h[(kk + 0) * 64 + lane];
        unsigned int w1_ = W3h[(kk + 1) * 64 + lane];
        unsigned int w2_ = W3h[(kk + 2) * 64 + lane];
        unsigned int w3_ = W3h[(kk + 3) * 64 + lane];
        g0 = __builtin_amdgcn_fdot2(as_h2(br.x), as_h2(w0_), g0, false);
        g1 = __builtin_amdgcn_fdot2(as_h2(br.y), as_h2(w1_), g1, false);
        g2 = __builtin_amdgcn_fdot2(as_h2(br.z), as_h2(w2_), g2, false);
        g3 = __builtin_amdgcn_fdot2(as_h2(br.w), as_h2(w3_), g3, false);
    }
    float g = fmaxf((g0 + g1) + (g2 + g3), 0.f);
    float2 w4 = ((const float2*)W4)[lane];
    float l0 = g * w4.x, l1 = g * w4.y;
    #pragma unroll
    for (int m = 1; m < 64; m <<= 1) {
        l0 += __shfl_xor(l0, m, 64);
        l1 += __shfl_xor(l1, m, 64);
    }
    if (lane == 0) out[node] = make_float2(l0 + b4[0], l1 + b4[1]);
}

// ----------------------------- launch --------------------------------------

extern "C" void kernel_launch(void* const* d_in, const int* in_sizes, int n_in,
                              void* d_out, int out_size, void* d_ws, size_t ws_size,
                              hipStream_t stream) {
    const float* in_feat = (const float*)d_in[0];
    const int*   src     = (const int*)d_in[1];
    const int*   dst     = (const int*)d_in[2];
    const float* W1   = (const float*)d_in[3];
    const float* b1   = (const float*)d_in[4];
    const float* W2   = (const float*)d_in[5];
    const float* b2   = (const float*)d_in[6];
    const float* Wres = (const float*)d_in[7];
    const float* bres = (const float*)d_in[8];
    const float* Wattn = (const float*)d_in[9];
    const float* battn = (const float*)d_in[10];
    const float* Wf1  = (const float*)d_in[11];
    const float* bf1  = (const float*)d_in[12];
    const float* Wf2  = (const float*)d_in[13];
    const float* bf2  = (const float*)d_in[14];
    const float* W3   = (const float*)d_in[15];
    const float* b3   = (const float*)d_in[16];
    const float* W4   = (const float*)d_in[17];
    const float* b4   = (const float*)d_in[18];

    const int N = in_sizes[0] / 128;
    const int E = in_sizes[1];
    const int B = (N + BNODES - 1) >> BSHIFT;

    char* p = (char*)d_ws;
    auto take = [&](size_t bytes) -> char* {
        char* r = p;
        p += (bytes + 255) & ~(size_t)255;
        return r;
    };
    int*   bucketCount  = (int*)take((size_t)(B + 1) * 4);
    int*   bucketPtr    = (int*)take((size_t)(B + 1) * 4);
    int*   bucketCursor = (int*)take((size_t)(B + 1) * 4);
    int*   rowPtr       = (int*)take((size_t)(N + 1) * 4);
    int*   degN         = (int*)take((size_t)N * 4);
    float* dinv         = (float*)take((size_t)N * 4);
    int*   srcSorted    = (int*)take((size_t)E * 4);
    int*   ebuf         = (int*)take((size_t)E * 4);
    float* thv          = (float*)take((size_t)N * 4);
    float* tav          = (float*)take((size_t)N * 4);
    unsigned int* Wf1h  = (unsigned int*)take((size_t)4096 * 4);
    unsigned int* W3h   = (unsigned int*)take((size_t)2048 * 4);
    unsigned int* W2h   = (unsigned int*)take((size_t)2048 * 4);
    unsigned int* Wresh = (unsigned int*)take((size_t)2048 * 4);
    float* h1  = (float*)take((size_t)N * 256);
    float* h   = (float*)take((size_t)N * 256);
    float* hs  = (float*)take((size_t)N * 128);   // f16, 64 halves/row
    float* res = (float*)take((size_t)N * 256);
    float* u1  = (float*)take((size_t)N * 256);
    unsigned int* u1s = (unsigned int*)take((size_t)N * 64);  // fp8 rows

    int eb = (E + CHUNK - 1) / CHUNK;
    int dqb = (N + 255) / 256;              // dense1 256-node blocks
    int wnb = (N + 3) / 4;                  // wave-per-node blocks
    int spb = (N * 64 + 255) / 256;

    hipMemsetAsync(bucketCount, 0, (size_t)B * 4, stream);
    hipMemsetAsync(degN, 0, (size_t)N * 4, stream);

    // K1: bucket_count+deg || dense1 || pack_w
    fused1_k<<<eb + dqb + 40, 256, 0, stream>>>(dst, bucketCount, degN, E, B,
                                                in_feat, W1, b1, h1, N,
                                                Wf1, W3, W2, Wres,
                                                Wf1h, W3h, W2h, Wresh, eb, dqb);
    // K2: scan || dinv
    scan_dinv_k<<<1 + dqb, 256, 0, stream>>>(bucketCount, bucketPtr,
                                             bucketCursor, rowPtr,
                                             degN, dinv, B, N, E);
    // K3: scatter || dense2res (wave/node)
    fused3_k<<<eb + wnb, 256, 0, stream>>>(src, dst, bucketCursor, ebuf, E, B,
                                           h1, W2h, b2, Wresh, bres, Wattn,
                                           dinv, h, (__half*)hs, res, thv, N, eb);

    csr_build_k<<<B, 256, 0, stream>>>(ebuf, bucketPtr, rowPtr, srcSorted, N);

    spmm_k<<<spb, 256, 0, stream>>>((const float2*)hs, srcSorted, rowPtr, dinv,
                                    Wattn, (float4*)u1, u1s, tav, N);

    tail_k<<<wnb, 256, 0, stream>>>(u1s, srcSorted, rowPtr, dinv,
                                    h, u1, res, thv, tav, Wattn, battn,
                                    Wf1h, bf1, Wf2, bf2, W3h, b3, W4, b4,
                                    (float2*)d_out, N);
}